// Round 1
// baseline (442.985 us; speedup 1.0000x reference)
//
#include <hip/hip_runtime.h>
#include <hip/hip_bf16.h>

// out[i,f] = a[f]*x[i,f] + b[f], a/b repeated per group of 32 features.
// x: [2097152, 128] fp32. Memory-bound: 1 GiB in + 1 GiB out.
// Groups: 4 groups x 32 features. 128 feat/row = 32 float4/row,
// 8 float4/group -> group of float4 index i is ((i % 32) >> 3).

__global__ __launch_bounds__(256) void normalize_kernel(
    const float4* __restrict__ x,
    const float* __restrict__ x_min,
    const float* __restrict__ x_max,
    const float* __restrict__ u,
    const float* __restrict__ l,
    float4* __restrict__ out,
    long long n4)
{
    long long i = (long long)blockIdx.x * blockDim.x + threadIdx.x;
    const long long stride = (long long)gridDim.x * blockDim.x;

    // stride = gridDim*256 is a multiple of 32 -> group index is
    // loop-invariant per thread; hoist scale/shift out of the loop.
    const int g = (int)((i & 31) >> 3);
    const float s = (u[g] - l[g]) / (x_max[g] - x_min[g]);
    const float b = l[g] - x_min[g] * s;

    for (; i < n4; i += stride) {
        float4 v = x[i];
        float4 o;
        o.x = fmaf(s, v.x, b);
        o.y = fmaf(s, v.y, b);
        o.z = fmaf(s, v.z, b);
        o.w = fmaf(s, v.w, b);
        out[i] = o;
    }
}

extern "C" void kernel_launch(void* const* d_in, const int* in_sizes, int n_in,
                              void* d_out, int out_size, void* d_ws, size_t ws_size,
                              hipStream_t stream) {
    const float4* x     = (const float4*)d_in[0];
    const float*  x_min = (const float*)d_in[1];
    const float*  x_max = (const float*)d_in[2];
    const float*  u     = (const float*)d_in[3];
    const float*  l     = (const float*)d_in[4];
    float4* out = (float4*)d_out;

    const long long n4 = (long long)out_size / 4;  // total float4 elements

    const int block = 256;
    // 2048 blocks x 256 threads = 32 waves/CU on 256 CUs; grid-stride the rest.
    int grid = 2048;
    long long needed = (n4 + block - 1) / block;
    if (needed < grid) grid = (int)needed;

    normalize_kernel<<<grid, block, 0, stream>>>(x, x_min, x_max, u, l, out, n4);
}